// Round 5
// baseline (308.241 us; speedup 1.0000x reference)
//
#include <hip/hip_runtime.h>

#define N_NODES 50000
#define N_EDGES 500000
#define NUM_G   128
#define SCAN_NB 49               // ceil(50176/1024)
#define PN      (SCAN_NB * 1024) // 50176 padded node count
#define NCX     64               // edge chunks
#define ECH     7813             // 64*7813 >= 500000
#define RNG     8192             // nodes per LDS range for hist (32 KB)
#define NRY     7                // 7*8192 >= PN
#define HVB     (2 * NCX * NRY)  // 896 hist virtual blocks
#define CONVB   7813             // conv blocks (50000*160/4 / 256)
#define WPREPB  360
#define RNG_SC  2688             // scatter cursor window (10752 B = GEMM LDS)
#define NRY_SC  19               // 19*2688 = 51072 >= 50000
#define SCVB    (NCX * NRY_SC)   // 1216 scatter virtual blocks
#define GEMM_MB 782              // (50000+63)/64

typedef __attribute__((ext_vector_type(8))) short short8;
typedef __attribute__((ext_vector_type(4))) float f32x4;
typedef __attribute__((ext_vector_type(2))) float f32x2;

__device__ __forceinline__ unsigned f2bf(float x) {
    unsigned u = __float_as_uint(x);
    return (u + 0x7FFFu + ((u >> 16) & 1u)) >> 16;   // RNE
}
__device__ __forceinline__ float bf2f(unsigned h) {
    return __uint_as_float(h << 16);
}

// ============ D1: hist partials + fp32->bf16 conv + weight prep (one dispatch) ============
__device__ __forceinline__ void wprep_one(const float* __restrict__ W, unsigned short* __restrict__ WT,
                                          int t, int FIN, int F) {
    int n = t / FIN, k = t - n * FIN;
    int sel = n / F, c = n - sel * F;
    float v;
    if (sel == 0) v = W[(size_t)k * F + c] - W[(size_t)2 * FIN * F + (size_t)k * F + c];
    else          v = W[(size_t)sel * FIN * F + (size_t)k * F + c];
    WT[t] = (unsigned short)f2bf(v);
}

__global__ __launch_bounds__(256)
void prep_kernel(const int* __restrict__ src, const int* __restrict__ dst,
                 const float* __restrict__ ea,
                 float* __restrict__ pdeg, int* __restrict__ pcnt,
                 const float* __restrict__ x, unsigned short* __restrict__ Xb,
                 const float* __restrict__ W1, const float* __restrict__ W2,
                 const float* __restrict__ W3,
                 unsigned short* __restrict__ WT1, unsigned short* __restrict__ WT2,
                 unsigned short* __restrict__ WT3) {
    __shared__ unsigned lh[RNG];
    int vb = blockIdx.x, tid = threadIdx.x;
    if (vb < HVB) {
        bool isdeg = vb < NCX * NRY;
        int v2 = isdeg ? vb : vb - NCX * NRY;
        int xk = v2 & 63, y = v2 >> 6;
        int base = y * RNG;
        for (int i = tid; i < RNG; i += 256) lh[i] = 0u;
        __syncthreads();
        int e0 = xk * ECH, e1 = min(e0 + ECH, N_EDGES);
        if (isdeg) {
            for (int e = e0 + tid; e < e1; e += 256) {
                int s = src[e];
                if ((unsigned)(s - base) < RNG) atomicAdd((float*)&lh[s - base], ea[e]);
            }
        } else {
            for (int e = e0 + tid; e < e1; e += 256) {
                int d = dst[e];
                if ((unsigned)(d - base) < RNG) atomicAdd((int*)&lh[d - base], 1);
            }
        }
        __syncthreads();
        if (isdeg) {
            for (int i = tid; i < RNG; i += 256) {
                int n = base + i;
                if (n < PN) pdeg[(size_t)xk * PN + n] = ((float*)lh)[i];
            }
        } else {
            for (int i = tid; i < RNG; i += 256) {
                int n = base + i;
                if (n < PN) pcnt[(size_t)xk * PN + n] = ((int*)lh)[i];
            }
        }
    } else if (vb < HVB + CONVB) {
        int t = (vb - HVB) * 256 + tid;
        if (t < N_NODES * 160 / 4) {
            float4 v = reinterpret_cast<const float4*>(x)[t];
            ushort4 r;
            r.x = (unsigned short)f2bf(v.x);
            r.y = (unsigned short)f2bf(v.y);
            r.z = (unsigned short)f2bf(v.z);
            r.w = (unsigned short)f2bf(v.w);
            *reinterpret_cast<ushort4*>(Xb + (size_t)t * 4) = r;
        }
    } else {
        int t = (vb - HVB - CONVB) * 256 + tid;
        if (t < 61440)      wprep_one(W1, WT1, t, 160, 128);
        else if (t < 86016) wprep_one(W2, WT2, t - 61440, 128, 64);
        else if (t < 92160) wprep_one(W3, WT3, t - 86016, 64, 32);
    }
}

// ==== D2: reduce partials -> dinv, cnt; pcnt -> exclusive chunk-prefix; block sums ====
__global__ __launch_bounds__(256)
void reduce_scan_kernel(const float* __restrict__ pdeg, int* __restrict__ pcnt,
                        float* __restrict__ dinv, int* __restrict__ cnt,
                        int* __restrict__ partial) {
    int b = blockIdx.x, t = threadIdx.x;
    int i0 = b * 1024 + t * 4;
    float d0 = 0.f, d1 = 0.f, d2 = 0.f, d3 = 0.f;
    int r0 = 0, r1 = 0, r2 = 0, r3 = 0;
    for (int x = 0; x < NCX; ++x) {
        float4 pv = *reinterpret_cast<const float4*>(pdeg + (size_t)x * PN + i0);
        int4   cv = *reinterpret_cast<const int4*>(pcnt + (size_t)x * PN + i0);
        *reinterpret_cast<int4*>(pcnt + (size_t)x * PN + i0) = make_int4(r0, r1, r2, r3);
        d0 += pv.x; d1 += pv.y; d2 += pv.z; d3 += pv.w;
        r0 += cv.x; r1 += cv.y; r2 += cv.z; r3 += cv.w;
    }
    float dd[4] = {d0, d1, d2, d3};
    int   rr[4] = {r0, r1, r2, r3};
    int s = 0;
    #pragma unroll
    for (int j = 0; j < 4; ++j) {
        int n = i0 + j;
        if (n < N_NODES) {
            float dv = dd[j], r = 0.f;
            if (dv > 0.f) {
                r = rsqrtf(dv);
                r = r * (1.5f - 0.5f * dv * r * r);   // Newton refine to ~fp32 exact
            }
            dinv[n] = r;
            cnt[n] = rr[j];
            s += rr[j];
        } else {
            cnt[n] = 0;
        }
    }
    __shared__ int red[256];
    red[t] = s;
    __syncthreads();
    for (int off = 128; off > 0; off >>= 1) {
        if (t < off) red[t] += red[t + off];
        __syncthreads();
    }
    if (t == 0) partial[b] = red[0];
}

// ==== D3: final scan -> rowptr (each block redundantly wave-scans the 49 partials) ====
__global__ __launch_bounds__(256)
void scan_final_kernel(const int* __restrict__ cnt, const int* __restrict__ partial,
                       int* __restrict__ rowptr, int n) {
    int b = blockIdx.x, t = threadIdx.x;
    __shared__ int red[256];
    __shared__ int sh_off, sh_tot;
    if (t < 64) {
        int orig = (t < SCAN_NB) ? partial[t] : 0;
        int v = orig;
        #pragma unroll
        for (int off = 1; off < 64; off <<= 1) {
            int u = __shfl_up(v, off, 64);
            if (t >= off) v += u;
        }
        if (t == b) sh_off = v - orig;            // this block's exclusive offset (b < 49 <= 63)
        if (t == SCAN_NB - 1) sh_tot = v;         // grand total
    }
    __syncthreads();
    int4 v = reinterpret_cast<const int4*>(cnt)[b * 256 + t];
    int s = v.x + v.y + v.z + v.w;
    red[t] = s;
    __syncthreads();
    for (int off = 1; off < 256; off <<= 1) {
        int u = (t >= off) ? red[t - off] : 0;
        __syncthreads();
        red[t] += u;
        __syncthreads();
    }
    int excl = sh_off + ((t == 0) ? 0 : red[t - 1]);
    int i0 = b * 1024 + t * 4;
    if (i0 < n)     rowptr[i0]     = excl;
    if (i0 + 1 < n) rowptr[i0 + 1] = excl + v.x;
    if (i0 + 2 < n) rowptr[i0 + 2] = excl + v.x + v.y;
    if (i0 + 3 < n) rowptr[i0 + 3] = excl + v.x + v.y + v.z;
    if (b == SCAN_NB - 1 && t == 0) rowptr[n] = sh_tot;
}

// ==== shared bodies for the merged D4 dispatch ====
__device__ void scatter_body(int vb, const int* __restrict__ src, const int* __restrict__ dst,
                             const float* __restrict__ ea,
                             const int* __restrict__ rowptr, const int* __restrict__ pcnt,
                             int2* __restrict__ csr, unsigned char* smraw) {
    int* cursor = (int*)smraw;
    int tid = threadIdx.x;
    int x = vb & 63, y = vb >> 6;
    int base = y * RNG_SC;
    for (int i = tid; i < RNG_SC; i += 256) {
        int n = base + i;
        cursor[i] = (n < N_NODES) ? (rowptr[n] + pcnt[(size_t)x * PN + n]) : 0;
    }
    __syncthreads();
    int e0 = x * ECH, e1 = min(e0 + ECH, N_EDGES);
    for (int e = e0 + tid; e < e1; e += 256) {
        int d = dst[e];
        if ((unsigned)(d - base) < RNG_SC) {
            int pos = atomicAdd(&cursor[d - base], 1);   // LDS atomic
            int2 ew;
            ew.x = src[e];
            ew.y = __float_as_int(ea[e]);
            csr[pos] = ew;
        }
    }
}

// Unified-group GEMM: one block computes all 3 output groups for its 64 rows.
// A-fragments (afr) loaded ONCE, nt iterates over 3*NT tiles of WT.
template<int FIN, int F>
__device__ void gemm_body(int bx, const unsigned short* __restrict__ Xb,
                          const unsigned short* __restrict__ WT, const float* __restrict__ dinv,
                          unsigned short* __restrict__ Y0, unsigned short* __restrict__ Y1,
                          unsigned short* __restrict__ Y2, int nrows, unsigned char* smraw) {
    constexpr int KT = FIN / 32;
    constexpr int NT = F / 32;       // tiles per group
    constexpr int NTT = 3 * NT;      // total tiles
    constexpr int SA = FIN + 8;
    constexpr int F8 = FIN / 8;
    short* Bs = (short*)smraw;

    int tid = threadIdx.x;
    int lane = tid & 63, w = tid >> 6;
    int m0 = bx * 64;

    int colb = lane & 15;
    int q8 = (lane >> 4) << 3;
    int rq = (lane >> 4) << 2;
    int arow = m0 + w * 16 + colb;
    bool rok = arow < nrows;

    short8 afr[KT];
    #pragma unroll
    for (int kt = 0; kt < KT; ++kt) {
        short8 z = {0, 0, 0, 0, 0, 0, 0, 0};
        afr[kt] = rok ? *reinterpret_cast<const short8*>(Xb + (size_t)arow * FIN + (kt << 5) + q8) : z;
    }

    for (int nt = 0; nt < NTT; ++nt) {
        int n0 = nt << 5;
        __syncthreads();
        for (int span = tid; span < 32 * F8; span += 256) {
            int r = span / F8, c8 = (span - r * F8) << 3;
            int pr = (r < 16) ? (r << 1) : (((r - 16) << 1) + 1);
            *reinterpret_cast<uint4*>(&Bs[r * SA + c8]) =
                *reinterpret_cast<const uint4*>(WT + (size_t)(n0 + pr) * FIN + c8);
        }
        __syncthreads();

        f32x4 acc0 = {0.f, 0.f, 0.f, 0.f}, acc1 = acc0;
        #pragma unroll
        for (int kt = 0; kt < KT; ++kt) {
            short8 b0 = *reinterpret_cast<const short8*>(&Bs[colb * SA + (kt << 5) + q8]);
            short8 b1 = *reinterpret_cast<const short8*>(&Bs[(colb + 16) * SA + (kt << 5) + q8]);
            acc0 = __builtin_amdgcn_mfma_f32_16x16x32_bf16(afr[kt], b0, acc0, 0, 0, 0);
            acc1 = __builtin_amdgcn_mfma_f32_16x16x32_bf16(afr[kt], b1, acc1, 0, 0, 0);
        }

        int g = nt / NT;
        int ntg = nt - g * NT;
        unsigned short* Ys = (g == 0) ? Y0 : (g == 1) ? Y1 : Y2;
        int lc = (ntg << 5) + (colb << 1);
        #pragma unroll
        for (int r = 0; r < 4; ++r) {
            int orow = m0 + w * 16 + rq + r;
            if (orow < nrows) {
                float sc = (g == 2) ? dinv[orow] : 1.0f;
                unsigned pack = f2bf(acc0[r] * sc) | (f2bf(acc1[r] * sc) << 16);
                *reinterpret_cast<unsigned*>(Ys + (size_t)orow * F + lc) = pack;
            }
        }
    }
}

// ==== D4: merged scatter + layer-1 GEMM (independent inputs, no inter-block sync) ====
// LDS = 10752 B for BOTH halves -> 8 blocks/CU (wave-capped).
__global__ __launch_bounds__(256)
void sg_kernel(const int* __restrict__ src, const int* __restrict__ dst,
               const float* __restrict__ ea,
               const int* __restrict__ rowptr, const int* __restrict__ pcnt,
               int2* __restrict__ csr,
               const unsigned short* __restrict__ Xb, const unsigned short* __restrict__ WT1,
               const float* __restrict__ dinv,
               unsigned short* __restrict__ Y0, unsigned short* __restrict__ Y1,
               unsigned short* __restrict__ Y2) {
    __shared__ alignas(16) unsigned char sm[32 * (160 + 8) * 2];   // 10752 B
    int vb = blockIdx.x;
    if (vb < SCVB) {
        scatter_body(vb, src, dst, ea, rowptr, pcnt, csr, sm);
    } else {
        gemm_body<160, 128>(vb - SCVB, Xb, WT1, dinv, Y0, Y1, Y2, N_NODES, sm);
    }
}

// ==== layers 2/3 GEMM (unified groups) ====
template<int FIN, int F>
__launch_bounds__(256)
__global__ void cheb_gemm(const unsigned short* __restrict__ Xb, const unsigned short* __restrict__ WT,
                          const float* __restrict__ dinv,
                          unsigned short* __restrict__ Y0, unsigned short* __restrict__ Y1,
                          unsigned short* __restrict__ Y2, int nrows) {
    __shared__ alignas(16) unsigned char sm[32 * (FIN + 8) * 2];
    gemm_body<FIN, F>(blockIdx.x, Xb, WT, dinv, Y0, Y1, Y2, nrows, sm);
}

// ============ bf16 CSR gathers: 2 adjacent rows per thread, fused edge stream ============
// Per edge: unpack 8 bf16 once, route into accA/accB via weight select (wA/wB).
__device__ __forceinline__ void acc8d(f32x2* accA, f32x2* accB, uint4 p, float wA, float wB) {
    f32x2 wa; wa[0] = wA; wa[1] = wA;
    f32x2 wb; wb[0] = wB; wb[1] = wB;
    f32x2 a;
    a[0] = __uint_as_float(p.x << 16); a[1] = __uint_as_float(p.x & 0xFFFF0000u);
    accA[0] += wa * a; accB[0] += wb * a;
    a[0] = __uint_as_float(p.y << 16); a[1] = __uint_as_float(p.y & 0xFFFF0000u);
    accA[1] += wa * a; accB[1] += wb * a;
    a[0] = __uint_as_float(p.z << 16); a[1] = __uint_as_float(p.z & 0xFFFF0000u);
    accA[2] += wa * a; accB[2] += wb * a;
    a[0] = __uint_as_float(p.w << 16); a[1] = __uint_as_float(p.w & 0xFFFF0000u);
    accA[3] += wa * a; accB[3] += wb * a;
}

__device__ __forceinline__ void expand8(uint4 p, float* o) {
    o[0] = bf2f(p.x & 0xFFFFu);
    o[1] = __uint_as_float(p.x & 0xFFFF0000u);
    o[2] = bf2f(p.y & 0xFFFFu);
    o[3] = __uint_as_float(p.y & 0xFFFF0000u);
    o[4] = bf2f(p.z & 0xFFFFu);
    o[5] = __uint_as_float(p.z & 0xFFFF0000u);
    o[6] = bf2f(p.w & 0xFFFFu);
    o[7] = __uint_as_float(p.w & 0xFFFF0000u);
}

// MODE 0: U' = dv*(Y - 2*dv*t) ;  MODE 1: relu(Y - dv*t + bias)
template<int F, int MODE>
__launch_bounds__(256)
__global__ void gather_kernel(const unsigned short* __restrict__ X, const int2* __restrict__ csr,
                              const int* __restrict__ rowptr, const float* __restrict__ dinv,
                              const unsigned short* __restrict__ Y, const float* __restrict__ bias,
                              unsigned short* __restrict__ O, int n) {
    constexpr int FQ8 = F >> 3;            // threads per row: 16/8/4
    constexpr int GPB = 256 / FQ8;         // row-pair groups per block: 16/32/64
    constexpr int RPB = 2 * GPB;           // rows per block: 32/64/128
    constexpr int CAP = 2048;              // staged edge capacity (16 KB; worst F=32 block ~Poisson(1280))
    __shared__ int2 scsr[CAP];
    __shared__ int srp[RPB + 1];
    int tid = threadIdx.x;
    int db0 = blockIdx.x * RPB;
    for (int i = tid; i <= RPB; i += 256) srp[i] = rowptr[min(db0 + i, n)];
    __syncthreads();
    int ebeg = srp[0];
    int ecnt = srp[RPB] - ebeg;
    bool staged = ecnt <= CAP;
    if (staged) {
        for (int i = tid; i < ecnt; i += 256)
            scsr[i] = csr[ebeg + i];
    }
    __syncthreads();

    int grp = tid / FQ8;
    int rA = db0 + 2 * grp;                // this thread owns rows rA, rA+1
    if (rA >= n) return;
    int f8 = (tid - grp * FQ8) << 3;
    f32x2 accA[4], accB[4];
    #pragma unroll
    for (int j = 0; j < 4; ++j) {
        accA[j][0] = 0.f; accA[j][1] = 0.f;
        accB[j][0] = 0.f; accB[j][1] = 0.f;
    }

    if (staged) {
        int beg   = srp[2 * grp]     - ebeg;
        int split = srp[2 * grp + 1] - ebeg;
        int end   = srp[2 * grp + 2] - ebeg;
        int i = beg;
        for (; i + 7 < end; i += 8) {      // 8 independent X-rows in flight, spanning both rows
            int2 e0 = scsr[i],     e1 = scsr[i + 1], e2 = scsr[i + 2], e3 = scsr[i + 3];
            int2 e4 = scsr[i + 4], e5 = scsr[i + 5], e6 = scsr[i + 6], e7 = scsr[i + 7];
            uint4 p0 = *reinterpret_cast<const uint4*>(X + (size_t)e0.x * F + f8);
            uint4 p1 = *reinterpret_cast<const uint4*>(X + (size_t)e1.x * F + f8);
            uint4 p2 = *reinterpret_cast<const uint4*>(X + (size_t)e2.x * F + f8);
            uint4 p3 = *reinterpret_cast<const uint4*>(X + (size_t)e3.x * F + f8);
            uint4 p4 = *reinterpret_cast<const uint4*>(X + (size_t)e4.x * F + f8);
            uint4 p5 = *reinterpret_cast<const uint4*>(X + (size_t)e5.x * F + f8);
            uint4 p6 = *reinterpret_cast<const uint4*>(X + (size_t)e6.x * F + f8);
            uint4 p7 = *reinterpret_cast<const uint4*>(X + (size_t)e7.x * F + f8);
            float w0 = __int_as_float(e0.y), w1 = __int_as_float(e1.y);
            float w2 = __int_as_float(e2.y), w3 = __int_as_float(e3.y);
            float w4 = __int_as_float(e4.y), w5 = __int_as_float(e5.y);
            float w6 = __int_as_float(e6.y), w7 = __int_as_float(e7.y);
            float a0 = (i + 0 < split) ? w0 : 0.f;
            float a1 = (i + 1 < split) ? w1 : 0.f;
            float a2 = (i + 2 < split) ? w2 : 0.f;
            float a3 = (i + 3 < split) ? w3 : 0.f;
            float a4 = (i + 4 < split) ? w4 : 0.f;
            float a5 = (i + 5 < split) ? w5 : 0.f;
            float a6 = (i + 6 < split) ? w6 : 0.f;
            float a7 = (i + 7 < split) ? w7 : 0.f;
            acc8d(accA, accB, p0, a0, w0 - a0);
            acc8d(accA, accB, p1, a1, w1 - a1);
            acc8d(accA, accB, p2, a2, w2 - a2);
            acc8d(accA, accB, p3, a3, w3 - a3);
            acc8d(accA, accB, p4, a4, w4 - a4);
            acc8d(accA, accB, p5, a5, w5 - a5);
            acc8d(accA, accB, p6, a6, w6 - a6);
            acc8d(accA, accB, p7, a7, w7 - a7);
        }
        for (; i + 3 < end; i += 4) {
            int2 e0 = scsr[i], e1 = scsr[i + 1], e2 = scsr[i + 2], e3 = scsr[i + 3];
            uint4 p0 = *reinterpret_cast<const uint4*>(X + (size_t)e0.x * F + f8);
            uint4 p1 = *reinterpret_cast<const uint4*>(X + (size_t)e1.x * F + f8);
            uint4 p2 = *reinterpret_cast<const uint4*>(X + (size_t)e2.x * F + f8);
            uint4 p3 = *reinterpret_cast<const uint4*>(X + (size_t)e3.x * F + f8);
            float w0 = __int_as_float(e0.y), w1 = __int_as_float(e1.y);
            float w2 = __int_as_float(e2.y), w3 = __int_as_float(e3.y);
            float a0 = (i + 0 < split) ? w0 : 0.f;
            float a1 = (i + 1 < split) ? w1 : 0.f;
            float a2 = (i + 2 < split) ? w2 : 0.f;
            float a3 = (i + 3 < split) ? w3 : 0.f;
            acc8d(accA, accB, p0, a0, w0 - a0);
            acc8d(accA, accB, p1, a1, w1 - a1);
            acc8d(accA, accB, p2, a2, w2 - a2);
            acc8d(accA, accB, p3, a3, w3 - a3);
        }
        for (; i < end; ++i) {
            int2 e = scsr[i];
            uint4 p = *reinterpret_cast<const uint4*>(X + (size_t)e.x * F + f8);
            float wv = __int_as_float(e.y);
            float a = (i < split) ? wv : 0.f;
            acc8d(accA, accB, p, a, wv - a);
        }
    } else {                               // fallback: direct global (never expected)
        int beg   = srp[2 * grp];
        int split = srp[2 * grp + 1];
        int end   = srp[2 * grp + 2];
        for (int i = beg; i < end; ++i) {
            int2 e = csr[i];
            uint4 p = *reinterpret_cast<const uint4*>(X + (size_t)e.x * F + f8);
            float wv = __int_as_float(e.y);
            float a = (i < split) ? wv : 0.f;
            acc8d(accA, accB, p, a, wv - a);
        }
    }

    // epilogue for each owned row (named accs -> compile-time indexing, no scratch)
    {
        float accs[8];
        #pragma unroll
        for (int j = 0; j < 8; ++j) accs[j] = accA[j >> 1][j & 1];
        float y[8];
        expand8(*reinterpret_cast<const uint4*>(Y + (size_t)rA * F + f8), y);
        float dv = dinv[rA];
        float v[8];
        if (MODE == 0) {
            float dv2 = 2.f * dv;
            #pragma unroll
            for (int j = 0; j < 8; ++j) v[j] = dv * (y[j] - dv2 * accs[j]);
        } else {
            float4 ba = *reinterpret_cast<const float4*>(bias + f8);
            float4 bb = *reinterpret_cast<const float4*>(bias + f8 + 4);
            v[0] = fmaxf(y[0] - dv * accs[0] + ba.x, 0.f);
            v[1] = fmaxf(y[1] - dv * accs[1] + ba.y, 0.f);
            v[2] = fmaxf(y[2] - dv * accs[2] + ba.z, 0.f);
            v[3] = fmaxf(y[3] - dv * accs[3] + ba.w, 0.f);
            v[4] = fmaxf(y[4] - dv * accs[4] + bb.x, 0.f);
            v[5] = fmaxf(y[5] - dv * accs[5] + bb.y, 0.f);
            v[6] = fmaxf(y[6] - dv * accs[6] + bb.z, 0.f);
            v[7] = fmaxf(y[7] - dv * accs[7] + bb.w, 0.f);
        }
        uint4 o;
        o.x = f2bf(v[0]) | (f2bf(v[1]) << 16);
        o.y = f2bf(v[2]) | (f2bf(v[3]) << 16);
        o.z = f2bf(v[4]) | (f2bf(v[5]) << 16);
        o.w = f2bf(v[6]) | (f2bf(v[7]) << 16);
        *reinterpret_cast<uint4*>(O + (size_t)rA * F + f8) = o;
    }
    int rB = rA + 1;
    if (rB < n) {
        float accs[8];
        #pragma unroll
        for (int j = 0; j < 8; ++j) accs[j] = accB[j >> 1][j & 1];
        float y[8];
        expand8(*reinterpret_cast<const uint4*>(Y + (size_t)rB * F + f8), y);
        float dv = dinv[rB];
        float v[8];
        if (MODE == 0) {
            float dv2 = 2.f * dv;
            #pragma unroll
            for (int j = 0; j < 8; ++j) v[j] = dv * (y[j] - dv2 * accs[j]);
        } else {
            float4 ba = *reinterpret_cast<const float4*>(bias + f8);
            float4 bb = *reinterpret_cast<const float4*>(bias + f8 + 4);
            v[0] = fmaxf(y[0] - dv * accs[0] + ba.x, 0.f);
            v[1] = fmaxf(y[1] - dv * accs[1] + ba.y, 0.f);
            v[2] = fmaxf(y[2] - dv * accs[2] + ba.z, 0.f);
            v[3] = fmaxf(y[3] - dv * accs[3] + ba.w, 0.f);
            v[4] = fmaxf(y[4] - dv * accs[4] + bb.x, 0.f);
            v[5] = fmaxf(y[5] - dv * accs[5] + bb.y, 0.f);
            v[6] = fmaxf(y[6] - dv * accs[6] + bb.z, 0.f);
            v[7] = fmaxf(y[7] - dv * accs[7] + bb.w, 0.f);
        }
        uint4 o;
        o.x = f2bf(v[0]) | (f2bf(v[1]) << 16);
        o.y = f2bf(v[2]) | (f2bf(v[3]) << 16);
        o.z = f2bf(v[4]) | (f2bf(v[5]) << 16);
        o.w = f2bf(v[6]) | (f2bf(v[7]) << 16);
        *reinterpret_cast<uint4*>(O + (size_t)rB * F + f8) = o;
    }
}

// ============ pooling + final linear ============
__device__ __forceinline__ int lower_bound_dev(const int* __restrict__ a, int n, int v) {
    int lo = 0, hi = n;
    while (lo < hi) {
        int mid = (lo + hi) >> 1;
        if (a[mid] < v) lo = mid + 1; else hi = mid;
    }
    return lo;
}

__global__ void pool_kernel(const unsigned short* __restrict__ H, const int* __restrict__ batch,
                            const float* __restrict__ Wl, const float* __restrict__ bl,
                            float* __restrict__ out, int n) {
    int g = blockIdx.x;
    int start = lower_bound_dev(batch, n, g);
    int end   = lower_bound_dev(batch, n, g + 1);
    int tid = threadIdx.x;
    int f = tid & 31;
    int sub = tid >> 5;
    float acc = 0.0f;
    for (int i = start + sub; i < end; i += 8)
        acc += bf2f((unsigned)H[(size_t)i * 32 + f]);
    __shared__ float red[256];
    red[tid] = acc;
    __syncthreads();
    if (tid < 128) red[tid] += red[tid + 128];
    __syncthreads();
    if (tid < 64) red[tid] += red[tid + 64];
    __syncthreads();
    if (tid < 32) red[tid] += red[tid + 32];
    __syncthreads();
    if (tid < 2) {
        int cnt = end - start;
        float inv = 1.0f / (float)(cnt > 0 ? cnt : 1);
        float o = bl[tid];
        for (int f2 = 0; f2 < 32; ++f2)
            o += red[f2] * inv * Wl[f2 * 2 + tid];
        out[g * 2 + tid] = o;
    }
}

extern "C" void kernel_launch(void* const* d_in, const int* in_sizes, int n_in,
                              void* d_out, int out_size, void* d_ws, size_t ws_size,
                              hipStream_t stream) {
    const float* x     = (const float*)d_in[0];
    const int*   ei    = (const int*)d_in[1];
    const float* ea    = (const float*)d_in[2];
    const int*   batch = (const int*)d_in[3];
    const float* W1 = (const float*)d_in[4];
    const float* b1 = (const float*)d_in[5];
    const float* W2 = (const float*)d_in[6];
    const float* b2 = (const float*)d_in[7];
    const float* W3 = (const float*)d_in[8];
    const float* b3 = (const float*)d_in[9];
    const float* Wl = (const float*)d_in[10];
    const float* bl = (const float*)d_in[11];
    float* out = (float*)d_out;
    char* ws = (char*)d_ws;

    const int* src = ei;
    const int* dst = ei + N_EDGES;

    size_t off = 0;
    auto alloc = [&](size_t bytes) { char* p = ws + off; off += (bytes + 255) & ~(size_t)255; return p; };
    float* pdeg    = (float*)alloc((size_t)NCX * PN * 4);
    int*   pcnt    = (int*)  alloc((size_t)NCX * PN * 4);
    float* dinv    = (float*)alloc(N_NODES * 4);
    int*   cnt     = (int*)  alloc((size_t)PN * 4);
    int*   partial = (int*)  alloc(SCAN_NB * 4);
    int*   rowptr  = (int*)  alloc((N_NODES + 1) * 4);
    int2*  csr     = (int2*) alloc((size_t)N_EDGES * 8);
    unsigned short* Xb  = (unsigned short*)alloc((size_t)N_NODES * 160 * 2);
    unsigned short* Y0  = (unsigned short*)alloc((size_t)N_NODES * 128 * 2);
    unsigned short* Y1  = (unsigned short*)alloc((size_t)N_NODES * 128 * 2);
    unsigned short* Y2  = (unsigned short*)alloc((size_t)N_NODES * 128 * 2);
    unsigned short* U   = (unsigned short*)alloc((size_t)N_NODES * 128 * 2);
    unsigned short* WT1 = (unsigned short*)alloc((size_t)384 * 160 * 2);
    unsigned short* WT2 = (unsigned short*)alloc((size_t)192 * 128 * 2);
    unsigned short* WT3 = (unsigned short*)alloc((size_t)96 * 64 * 2);

    const int BT = 256;

    // D1: hist + conv + wprep
    prep_kernel<<<HVB + CONVB + WPREPB, BT, 0, stream>>>(src, dst, ea, pdeg, pcnt,
                                                         x, Xb, W1, W2, W3, WT1, WT2, WT3);
    // D2: reduce + block sums
    reduce_scan_kernel<<<SCAN_NB, BT, 0, stream>>>(pdeg, pcnt, dinv, cnt, partial);
    // D3: final scan -> rowptr (offsets computed redundantly per block)
    scan_final_kernel<<<SCAN_NB, BT, 0, stream>>>(cnt, partial, rowptr, N_NODES);
    // D4: scatter + layer-1 GEMM merged (10752 B LDS, unified output groups)
    sg_kernel<<<SCVB + GEMM_MB, BT, 0, stream>>>(src, dst, ea, rowptr, pcnt, csr,
                                                 Xb, WT1, dinv, Y0, Y1, Y2);

    auto gb = [&](int F) { int RPB = 2 * (256 / (F / 8)); return (N_NODES + RPB - 1) / RPB; };

    gather_kernel<128, 0><<<gb(128), BT, 0, stream>>>(Y2, csr, rowptr, dinv, Y1, nullptr, U, N_NODES);
    gather_kernel<128, 1><<<gb(128), BT, 0, stream>>>(U, csr, rowptr, dinv, Y0, b1, Xb, N_NODES);

    cheb_gemm<128, 64><<<GEMM_MB, BT, 0, stream>>>(Xb, WT2, dinv, Y0, Y1, Y2, N_NODES);
    gather_kernel<64, 0><<<gb(64), BT, 0, stream>>>(Y2, csr, rowptr, dinv, Y1, nullptr, U, N_NODES);
    gather_kernel<64, 1><<<gb(64), BT, 0, stream>>>(U, csr, rowptr, dinv, Y0, b2, Xb, N_NODES);

    cheb_gemm<64, 32><<<GEMM_MB, BT, 0, stream>>>(Xb, WT3, dinv, Y0, Y1, Y2, N_NODES);
    gather_kernel<32, 0><<<gb(32), BT, 0, stream>>>(Y2, csr, rowptr, dinv, Y1, nullptr, U, N_NODES);
    gather_kernel<32, 1><<<gb(32), BT, 0, stream>>>(U, csr, rowptr, dinv, Y0, b3, Xb, N_NODES);

    pool_kernel<<<NUM_G, BT, 0, stream>>>(Xb, batch, Wl, bl, out, N_NODES);
}

// Round 6
// 293.211 us; speedup vs baseline: 1.0513x; 1.0513x over previous
//
#include <hip/hip_runtime.h>

#define N_NODES 50000
#define N_EDGES 500000
#define NUM_G   128
#define SCAN_NB 49               // ceil(50176/1024)
#define PN      (SCAN_NB * 1024) // 50176 padded node count
#define NCX     32               // edge chunks
#define NCX_SH  5
#define ECH     15628            // 32*15628 >= 500000, ECH % 4 == 0
#define RNG     8192             // nodes per LDS range for hist (32 KB)
#define NRY     7                // 7*8192 >= PN
#define HVB     (2 * NCX * NRY)  // 448 hist virtual blocks
#define CONVB   7813             // conv blocks (50000*160/4 / 256)
#define WPREPB  360
#define RNG_SC  2688             // scatter cursor window (10752 B = GEMM LDS)
#define NRY_SC  19               // 19*2688 = 51072 >= 50000
#define SCVB    (NCX * NRY_SC)   // 608 scatter virtual blocks
#define GEMM_MB 782              // (50000+63)/64

typedef __attribute__((ext_vector_type(8))) short short8;
typedef __attribute__((ext_vector_type(4))) float f32x4;
typedef __attribute__((ext_vector_type(2))) float f32x2;

__device__ __forceinline__ unsigned f2bf(float x) {
    unsigned u = __float_as_uint(x);
    return (u + 0x7FFFu + ((u >> 16) & 1u)) >> 16;   // RNE
}
__device__ __forceinline__ float bf2f(unsigned h) {
    return __uint_as_float(h << 16);
}

// ============ D1: hist partials + fp32->bf16 conv + weight prep (one dispatch) ============
__device__ __forceinline__ void wprep_one(const float* __restrict__ W, unsigned short* __restrict__ WT,
                                          int t, int FIN, int F) {
    int n = t / FIN, k = t - n * FIN;
    int sel = n / F, c = n - sel * F;
    float v;
    if (sel == 0) v = W[(size_t)k * F + c] - W[(size_t)2 * FIN * F + (size_t)k * F + c];
    else          v = W[(size_t)sel * FIN * F + (size_t)k * F + c];
    WT[t] = (unsigned short)f2bf(v);
}

__global__ __launch_bounds__(256)
void prep_kernel(const int* __restrict__ src, const int* __restrict__ dst,
                 const float* __restrict__ ea,
                 float* __restrict__ pdeg, int* __restrict__ pcnt,
                 const float* __restrict__ x, unsigned short* __restrict__ Xb,
                 const float* __restrict__ W1, const float* __restrict__ W2,
                 const float* __restrict__ W3,
                 unsigned short* __restrict__ WT1, unsigned short* __restrict__ WT2,
                 unsigned short* __restrict__ WT3) {
    __shared__ unsigned lh[RNG];
    int vb = blockIdx.x, tid = threadIdx.x;
    if (vb < HVB) {
        bool isdeg = vb < NCX * NRY;
        int v2 = isdeg ? vb : vb - NCX * NRY;
        int xk = v2 & (NCX - 1), y = v2 >> NCX_SH;
        int base = y * RNG;
        for (int i = tid; i < RNG; i += 256) lh[i] = 0u;
        __syncthreads();
        int e0 = xk * ECH, e1 = min(e0 + ECH, N_EDGES);
        // e0 % 4 == 0 and e1 is either e0+ECH (mult of 4) or 500000 (mult of 4):
        // int4 quads never straddle e1.
        if (isdeg) {
            for (int e = e0 + tid * 4; e < e1; e += 1024) {
                int4 s4 = *reinterpret_cast<const int4*>(src + e);
                if ((unsigned)(s4.x - base) < RNG) atomicAdd((float*)&lh[s4.x - base], ea[e]);
                if ((unsigned)(s4.y - base) < RNG) atomicAdd((float*)&lh[s4.y - base], ea[e + 1]);
                if ((unsigned)(s4.z - base) < RNG) atomicAdd((float*)&lh[s4.z - base], ea[e + 2]);
                if ((unsigned)(s4.w - base) < RNG) atomicAdd((float*)&lh[s4.w - base], ea[e + 3]);
            }
        } else {
            for (int e = e0 + tid * 4; e < e1; e += 1024) {
                int4 d4 = *reinterpret_cast<const int4*>(dst + e);
                if ((unsigned)(d4.x - base) < RNG) atomicAdd((int*)&lh[d4.x - base], 1);
                if ((unsigned)(d4.y - base) < RNG) atomicAdd((int*)&lh[d4.y - base], 1);
                if ((unsigned)(d4.z - base) < RNG) atomicAdd((int*)&lh[d4.z - base], 1);
                if ((unsigned)(d4.w - base) < RNG) atomicAdd((int*)&lh[d4.w - base], 1);
            }
        }
        __syncthreads();
        if (isdeg) {
            for (int i = tid; i < RNG; i += 256) {
                int n = base + i;
                if (n < PN) pdeg[(size_t)xk * PN + n] = ((float*)lh)[i];
            }
        } else {
            for (int i = tid; i < RNG; i += 256) {
                int n = base + i;
                if (n < PN) pcnt[(size_t)xk * PN + n] = ((int*)lh)[i];
            }
        }
    } else if (vb < HVB + CONVB) {
        int t = (vb - HVB) * 256 + tid;
        if (t < N_NODES * 160 / 4) {
            float4 v = reinterpret_cast<const float4*>(x)[t];
            ushort4 r;
            r.x = (unsigned short)f2bf(v.x);
            r.y = (unsigned short)f2bf(v.y);
            r.z = (unsigned short)f2bf(v.z);
            r.w = (unsigned short)f2bf(v.w);
            *reinterpret_cast<ushort4*>(Xb + (size_t)t * 4) = r;
        }
    } else {
        int t = (vb - HVB - CONVB) * 256 + tid;
        if (t < 61440)      wprep_one(W1, WT1, t, 160, 128);
        else if (t < 86016) wprep_one(W2, WT2, t - 61440, 128, 64);
        else if (t < 92160) wprep_one(W3, WT3, t - 86016, 64, 32);
    }
}

// ==== D2: reduce partials -> dinv, cnt; pcnt -> exclusive chunk-prefix; block sums ====
__global__ __launch_bounds__(256)
void reduce_scan_kernel(const float* __restrict__ pdeg, int* __restrict__ pcnt,
                        float* __restrict__ dinv, int* __restrict__ cnt,
                        int* __restrict__ partial) {
    int b = blockIdx.x, t = threadIdx.x;
    int i0 = b * 1024 + t * 4;
    float d0 = 0.f, d1 = 0.f, d2 = 0.f, d3 = 0.f;
    int r0 = 0, r1 = 0, r2 = 0, r3 = 0;
    for (int x = 0; x < NCX; ++x) {
        float4 pv = *reinterpret_cast<const float4*>(pdeg + (size_t)x * PN + i0);
        int4   cv = *reinterpret_cast<const int4*>(pcnt + (size_t)x * PN + i0);
        *reinterpret_cast<int4*>(pcnt + (size_t)x * PN + i0) = make_int4(r0, r1, r2, r3);
        d0 += pv.x; d1 += pv.y; d2 += pv.z; d3 += pv.w;
        r0 += cv.x; r1 += cv.y; r2 += cv.z; r3 += cv.w;
    }
    float dd[4] = {d0, d1, d2, d3};
    int   rr[4] = {r0, r1, r2, r3};
    int s = 0;
    #pragma unroll
    for (int j = 0; j < 4; ++j) {
        int n = i0 + j;
        if (n < N_NODES) {
            float dv = dd[j], r = 0.f;
            if (dv > 0.f) {
                r = rsqrtf(dv);
                r = r * (1.5f - 0.5f * dv * r * r);   // Newton refine to ~fp32 exact
            }
            dinv[n] = r;
            cnt[n] = rr[j];
            s += rr[j];
        } else {
            cnt[n] = 0;
        }
    }
    __shared__ int red[256];
    red[t] = s;
    __syncthreads();
    for (int off = 128; off > 0; off >>= 1) {
        if (t < off) red[t] += red[t + off];
        __syncthreads();
    }
    if (t == 0) partial[b] = red[0];
}

// ==== D3: final scan -> rowptr (each block redundantly wave-scans the 49 partials) ====
__global__ __launch_bounds__(256)
void scan_final_kernel(const int* __restrict__ cnt, const int* __restrict__ partial,
                       int* __restrict__ rowptr, int n) {
    int b = blockIdx.x, t = threadIdx.x;
    __shared__ int red[256];
    __shared__ int sh_off, sh_tot;
    if (t < 64) {
        int orig = (t < SCAN_NB) ? partial[t] : 0;
        int v = orig;
        #pragma unroll
        for (int off = 1; off < 64; off <<= 1) {
            int u = __shfl_up(v, off, 64);
            if (t >= off) v += u;
        }
        if (t == b) sh_off = v - orig;            // this block's exclusive offset (b < 49 <= 63)
        if (t == SCAN_NB - 1) sh_tot = v;         // grand total
    }
    __syncthreads();
    int4 v = reinterpret_cast<const int4*>(cnt)[b * 256 + t];
    int s = v.x + v.y + v.z + v.w;
    red[t] = s;
    __syncthreads();
    for (int off = 1; off < 256; off <<= 1) {
        int u = (t >= off) ? red[t - off] : 0;
        __syncthreads();
        red[t] += u;
        __syncthreads();
    }
    int excl = sh_off + ((t == 0) ? 0 : red[t - 1]);
    int i0 = b * 1024 + t * 4;
    if (i0 < n)     rowptr[i0]     = excl;
    if (i0 + 1 < n) rowptr[i0 + 1] = excl + v.x;
    if (i0 + 2 < n) rowptr[i0 + 2] = excl + v.x + v.y;
    if (i0 + 3 < n) rowptr[i0 + 3] = excl + v.x + v.y + v.z;
    if (b == SCAN_NB - 1 && t == 0) rowptr[n] = sh_tot;
}

// ==== shared bodies for the merged D4 dispatch ====
__device__ void scatter_body(int vb, const int* __restrict__ src, const int* __restrict__ dst,
                             const float* __restrict__ ea,
                             const int* __restrict__ rowptr, const int* __restrict__ pcnt,
                             int2* __restrict__ csr, unsigned char* smraw) {
    int* cursor = (int*)smraw;
    int tid = threadIdx.x;
    int x = vb & (NCX - 1), y = vb >> NCX_SH;
    int base = y * RNG_SC;
    for (int i = tid; i < RNG_SC; i += 256) {
        int n = base + i;
        cursor[i] = (n < N_NODES) ? (rowptr[n] + pcnt[(size_t)x * PN + n]) : 0;
    }
    __syncthreads();
    int e0 = x * ECH, e1 = min(e0 + ECH, N_EDGES);
    for (int e = e0 + tid * 4; e < e1; e += 1024) {
        int4 d4 = *reinterpret_cast<const int4*>(dst + e);
        if ((unsigned)(d4.x - base) < RNG_SC) {
            int pos = atomicAdd(&cursor[d4.x - base], 1);
            csr[pos] = make_int2(src[e], __float_as_int(ea[e]));
        }
        if ((unsigned)(d4.y - base) < RNG_SC) {
            int pos = atomicAdd(&cursor[d4.y - base], 1);
            csr[pos] = make_int2(src[e + 1], __float_as_int(ea[e + 1]));
        }
        if ((unsigned)(d4.z - base) < RNG_SC) {
            int pos = atomicAdd(&cursor[d4.z - base], 1);
            csr[pos] = make_int2(src[e + 2], __float_as_int(ea[e + 2]));
        }
        if ((unsigned)(d4.w - base) < RNG_SC) {
            int pos = atomicAdd(&cursor[d4.w - base], 1);
            csr[pos] = make_int2(src[e + 3], __float_as_int(ea[e + 3]));
        }
    }
}

// Unified-group GEMM: one block computes all 3 output groups for its 64 rows.
template<int FIN, int F>
__device__ void gemm_body(int bx, const unsigned short* __restrict__ Xb,
                          const unsigned short* __restrict__ WT, const float* __restrict__ dinv,
                          unsigned short* __restrict__ Y0, unsigned short* __restrict__ Y1,
                          unsigned short* __restrict__ Y2, int nrows, unsigned char* smraw) {
    constexpr int KT = FIN / 32;
    constexpr int NT = F / 32;       // tiles per group
    constexpr int NTT = 3 * NT;      // total tiles
    constexpr int SA = FIN + 8;
    constexpr int F8 = FIN / 8;
    short* Bs = (short*)smraw;

    int tid = threadIdx.x;
    int lane = tid & 63, w = tid >> 6;
    int m0 = bx * 64;

    int colb = lane & 15;
    int q8 = (lane >> 4) << 3;
    int rq = (lane >> 4) << 2;
    int arow = m0 + w * 16 + colb;
    bool rok = arow < nrows;

    short8 afr[KT];
    #pragma unroll
    for (int kt = 0; kt < KT; ++kt) {
        short8 z = {0, 0, 0, 0, 0, 0, 0, 0};
        afr[kt] = rok ? *reinterpret_cast<const short8*>(Xb + (size_t)arow * FIN + (kt << 5) + q8) : z;
    }

    for (int nt = 0; nt < NTT; ++nt) {
        int n0 = nt << 5;
        __syncthreads();
        for (int span = tid; span < 32 * F8; span += 256) {
            int r = span / F8, c8 = (span - r * F8) << 3;
            int pr = (r < 16) ? (r << 1) : (((r - 16) << 1) + 1);
            *reinterpret_cast<uint4*>(&Bs[r * SA + c8]) =
                *reinterpret_cast<const uint4*>(WT + (size_t)(n0 + pr) * FIN + c8);
        }
        __syncthreads();

        f32x4 acc0 = {0.f, 0.f, 0.f, 0.f}, acc1 = acc0;
        #pragma unroll
        for (int kt = 0; kt < KT; ++kt) {
            short8 b0 = *reinterpret_cast<const short8*>(&Bs[colb * SA + (kt << 5) + q8]);
            short8 b1 = *reinterpret_cast<const short8*>(&Bs[(colb + 16) * SA + (kt << 5) + q8]);
            acc0 = __builtin_amdgcn_mfma_f32_16x16x32_bf16(afr[kt], b0, acc0, 0, 0, 0);
            acc1 = __builtin_amdgcn_mfma_f32_16x16x32_bf16(afr[kt], b1, acc1, 0, 0, 0);
        }

        int g = nt / NT;
        int ntg = nt - g * NT;
        unsigned short* Ys = (g == 0) ? Y0 : (g == 1) ? Y1 : Y2;
        int lc = (ntg << 5) + (colb << 1);
        #pragma unroll
        for (int r = 0; r < 4; ++r) {
            int orow = m0 + w * 16 + rq + r;
            if (orow < nrows) {
                float sc = (g == 2) ? dinv[orow] : 1.0f;
                unsigned pack = f2bf(acc0[r] * sc) | (f2bf(acc1[r] * sc) << 16);
                *reinterpret_cast<unsigned*>(Ys + (size_t)orow * F + lc) = pack;
            }
        }
    }
}

// ==== D4: merged scatter + layer-1 GEMM ====
__global__ __launch_bounds__(256)
void sg_kernel(const int* __restrict__ src, const int* __restrict__ dst,
               const float* __restrict__ ea,
               const int* __restrict__ rowptr, const int* __restrict__ pcnt,
               int2* __restrict__ csr,
               const unsigned short* __restrict__ Xb, const unsigned short* __restrict__ WT1,
               const float* __restrict__ dinv,
               unsigned short* __restrict__ Y0, unsigned short* __restrict__ Y1,
               unsigned short* __restrict__ Y2) {
    __shared__ alignas(16) unsigned char sm[32 * (160 + 8) * 2];   // 10752 B
    int vb = blockIdx.x;
    if (vb < SCVB) {
        scatter_body(vb, src, dst, ea, rowptr, pcnt, csr, sm);
    } else {
        gemm_body<160, 128>(vb - SCVB, Xb, WT1, dinv, Y0, Y1, Y2, N_NODES, sm);
    }
}

// ==== layers 2/3 GEMM (unified groups) ====
template<int FIN, int F>
__launch_bounds__(256)
__global__ void cheb_gemm(const unsigned short* __restrict__ Xb, const unsigned short* __restrict__ WT,
                          const float* __restrict__ dinv,
                          unsigned short* __restrict__ Y0, unsigned short* __restrict__ Y1,
                          unsigned short* __restrict__ Y2, int nrows) {
    __shared__ alignas(16) unsigned char sm[32 * (FIN + 8) * 2];
    gemm_body<FIN, F>(blockIdx.x, Xb, WT, dinv, Y0, Y1, Y2, nrows, sm);
}

// ============ bf16 CSR gathers: LDS-staged + 8-deep pipeline + length-sorted row assignment ============
// f32x2-packed accumulate: 4 lshl + 4 and + 4 v_pk_fma_f32 per 16B
__device__ __forceinline__ void acc8p(f32x2* acc, uint4 p, float wv) {
    f32x2 w2; w2[0] = wv; w2[1] = wv;
    f32x2 a0, a1, a2, a3;
    a0[0] = __uint_as_float(p.x << 16); a0[1] = __uint_as_float(p.x & 0xFFFF0000u);
    a1[0] = __uint_as_float(p.y << 16); a1[1] = __uint_as_float(p.y & 0xFFFF0000u);
    a2[0] = __uint_as_float(p.z << 16); a2[1] = __uint_as_float(p.z & 0xFFFF0000u);
    a3[0] = __uint_as_float(p.w << 16); a3[1] = __uint_as_float(p.w & 0xFFFF0000u);
    acc[0] += w2 * a0;
    acc[1] += w2 * a1;
    acc[2] += w2 * a2;
    acc[3] += w2 * a3;
}

__device__ __forceinline__ void expand8(uint4 p, float* o) {
    o[0] = bf2f(p.x & 0xFFFFu);
    o[1] = __uint_as_float(p.x & 0xFFFF0000u);
    o[2] = bf2f(p.y & 0xFFFFu);
    o[3] = __uint_as_float(p.y & 0xFFFF0000u);
    o[4] = bf2f(p.z & 0xFFFFu);
    o[5] = __uint_as_float(p.z & 0xFFFF0000u);
    o[6] = bf2f(p.w & 0xFFFFu);
    o[7] = __uint_as_float(p.w & 0xFFFF0000u);
}

// MODE 0: U' = dv*(Y - 2*dv*t) ;  MODE 1: relu(Y - dv*t + bias)
template<int F, int MODE>
__launch_bounds__(256)
__global__ void gather_kernel(const unsigned short* __restrict__ X, const int2* __restrict__ csr,
                              const int* __restrict__ rowptr, const float* __restrict__ dinv,
                              const unsigned short* __restrict__ Y, const float* __restrict__ bias,
                              unsigned short* __restrict__ O, int n) {
    constexpr int FQ8 = F >> 3;            // threads per row: 16/8/4
    constexpr int DPB = 256 / FQ8;         // rows per block: 16/32/64
    constexpr int CAP = 1280;              // staged edge capacity (10.2 KB; worst block ~Poisson(640))
    __shared__ int2 scsr[CAP];
    __shared__ int srp[DPB + 1];
    __shared__ int smap[DPB];              // rank -> row slot (length-sorted)
    int tid = threadIdx.x;
    int db0 = blockIdx.x * DPB;
    if (tid <= DPB) srp[tid] = rowptr[min(db0 + tid, n)];
    __syncthreads();
    int ebeg = srp[0];
    int ecnt = srp[DPB] - ebeg;
    bool staged = ecnt <= CAP;
    // rank rows by CSR length (ascending, ties by slot) so each wave's groups
    // carry near-equal edge counts -> minimal lockstep waste. Deterministic.
    if (tid < DPB) {
        int my = srp[tid + 1] - srp[tid];
        int rk = 0;
        for (int g2 = 0; g2 < DPB; ++g2) {
            int l2 = srp[g2 + 1] - srp[g2];
            rk += (l2 < my) || (l2 == my && g2 < tid);
        }
        smap[rk] = tid;
    }
    if (staged) {
        for (int i = tid; i < ecnt; i += 256)
            scsr[i] = csr[ebeg + i];
    }
    __syncthreads();

    int gq = tid / FQ8;
    int rr = smap[gq];                     // this group's (sorted) row slot
    int d = db0 + rr;
    if (d >= n) return;                    // zero-length pad rows sort to the front
    int f8 = (tid - gq * FQ8) << 3;
    f32x2 acc[4];
    #pragma unroll
    for (int j = 0; j < 4; ++j) { acc[j][0] = 0.f; acc[j][1] = 0.f; }

    if (staged) {
        int beg = srp[rr] - ebeg, end = srp[rr + 1] - ebeg;
        int i = beg;
        for (; i + 7 < end; i += 8) {      // 8 independent X-rows in flight
            int2 e0 = scsr[i],     e1 = scsr[i + 1], e2 = scsr[i + 2], e3 = scsr[i + 3];
            int2 e4 = scsr[i + 4], e5 = scsr[i + 5], e6 = scsr[i + 6], e7 = scsr[i + 7];
            uint4 p0 = *reinterpret_cast<const uint4*>(X + (size_t)e0.x * F + f8);
            uint4 p1 = *reinterpret_cast<const uint4*>(X + (size_t)e1.x * F + f8);
            uint4 p2 = *reinterpret_cast<const uint4*>(X + (size_t)e2.x * F + f8);
            uint4 p3 = *reinterpret_cast<const uint4*>(X + (size_t)e3.x * F + f8);
            uint4 p4 = *reinterpret_cast<const uint4*>(X + (size_t)e4.x * F + f8);
            uint4 p5 = *reinterpret_cast<const uint4*>(X + (size_t)e5.x * F + f8);
            uint4 p6 = *reinterpret_cast<const uint4*>(X + (size_t)e6.x * F + f8);
            uint4 p7 = *reinterpret_cast<const uint4*>(X + (size_t)e7.x * F + f8);
            acc8p(acc, p0, __int_as_float(e0.y));
            acc8p(acc, p1, __int_as_float(e1.y));
            acc8p(acc, p2, __int_as_float(e2.y));
            acc8p(acc, p3, __int_as_float(e3.y));
            acc8p(acc, p4, __int_as_float(e4.y));
            acc8p(acc, p5, __int_as_float(e5.y));
            acc8p(acc, p6, __int_as_float(e6.y));
            acc8p(acc, p7, __int_as_float(e7.y));
        }
        for (; i + 3 < end; i += 4) {
            int2 e0 = scsr[i], e1 = scsr[i + 1], e2 = scsr[i + 2], e3 = scsr[i + 3];
            uint4 p0 = *reinterpret_cast<const uint4*>(X + (size_t)e0.x * F + f8);
            uint4 p1 = *reinterpret_cast<const uint4*>(X + (size_t)e1.x * F + f8);
            uint4 p2 = *reinterpret_cast<const uint4*>(X + (size_t)e2.x * F + f8);
            uint4 p3 = *reinterpret_cast<const uint4*>(X + (size_t)e3.x * F + f8);
            acc8p(acc, p0, __int_as_float(e0.y));
            acc8p(acc, p1, __int_as_float(e1.y));
            acc8p(acc, p2, __int_as_float(e2.y));
            acc8p(acc, p3, __int_as_float(e3.y));
        }
        for (; i < end; ++i) {
            int2 e = scsr[i];
            uint4 p = *reinterpret_cast<const uint4*>(X + (size_t)e.x * F + f8);
            acc8p(acc, p, __int_as_float(e.y));
        }
    } else {                               // fallback: direct global (never expected)
        int beg = srp[rr], end = srp[rr + 1];
        for (int i = beg; i < end; ++i) {
            int2 e = csr[i];
            uint4 p = *reinterpret_cast<const uint4*>(X + (size_t)e.x * F + f8);
            acc8p(acc, p, __int_as_float(e.y));
        }
    }

    float accs[8];
    #pragma unroll
    for (int j = 0; j < 8; ++j) accs[j] = acc[j >> 1][j & 1];

    float y[8];
    expand8(*reinterpret_cast<const uint4*>(Y + (size_t)d * F + f8), y);
    float dv = dinv[d];
    float v[8];
    if (MODE == 0) {
        float dv2 = 2.f * dv;
        #pragma unroll
        for (int j = 0; j < 8; ++j) v[j] = dv * (y[j] - dv2 * accs[j]);
    } else {
        float4 ba = *reinterpret_cast<const float4*>(bias + f8);
        float4 bb = *reinterpret_cast<const float4*>(bias + f8 + 4);
        v[0] = fmaxf(y[0] - dv * accs[0] + ba.x, 0.f);
        v[1] = fmaxf(y[1] - dv * accs[1] + ba.y, 0.f);
        v[2] = fmaxf(y[2] - dv * accs[2] + ba.z, 0.f);
        v[3] = fmaxf(y[3] - dv * accs[3] + ba.w, 0.f);
        v[4] = fmaxf(y[4] - dv * accs[4] + bb.x, 0.f);
        v[5] = fmaxf(y[5] - dv * accs[5] + bb.y, 0.f);
        v[6] = fmaxf(y[6] - dv * accs[6] + bb.z, 0.f);
        v[7] = fmaxf(y[7] - dv * accs[7] + bb.w, 0.f);
    }
    uint4 o;
    o.x = f2bf(v[0]) | (f2bf(v[1]) << 16);
    o.y = f2bf(v[2]) | (f2bf(v[3]) << 16);
    o.z = f2bf(v[4]) | (f2bf(v[5]) << 16);
    o.w = f2bf(v[6]) | (f2bf(v[7]) << 16);
    *reinterpret_cast<uint4*>(O + (size_t)d * F + f8) = o;
}

// ============ pooling + final linear ============
__device__ __forceinline__ int lower_bound_dev(const int* __restrict__ a, int n, int v) {
    int lo = 0, hi = n;
    while (lo < hi) {
        int mid = (lo + hi) >> 1;
        if (a[mid] < v) lo = mid + 1; else hi = mid;
    }
    return lo;
}

__global__ void pool_kernel(const unsigned short* __restrict__ H, const int* __restrict__ batch,
                            const float* __restrict__ Wl, const float* __restrict__ bl,
                            float* __restrict__ out, int n) {
    int g = blockIdx.x;
    int start = lower_bound_dev(batch, n, g);
    int end   = lower_bound_dev(batch, n, g + 1);
    int tid = threadIdx.x;
    int f = tid & 31;
    int sub = tid >> 5;
    float acc = 0.0f;
    for (int i = start + sub; i < end; i += 8)
        acc += bf2f((unsigned)H[(size_t)i * 32 + f]);
    __shared__ float red[256];
    red[tid] = acc;
    __syncthreads();
    if (tid < 128) red[tid] += red[tid + 128];
    __syncthreads();
    if (tid < 64) red[tid] += red[tid + 64];
    __syncthreads();
    if (tid < 32) red[tid] += red[tid + 32];
    __syncthreads();
    if (tid < 2) {
        int cnt = end - start;
        float inv = 1.0f / (float)(cnt > 0 ? cnt : 1);
        float o = bl[tid];
        for (int f2 = 0; f2 < 32; ++f2)
            o += red[f2] * inv * Wl[f2 * 2 + tid];
        out[g * 2 + tid] = o;
    }
}

extern "C" void kernel_launch(void* const* d_in, const int* in_sizes, int n_in,
                              void* d_out, int out_size, void* d_ws, size_t ws_size,
                              hipStream_t stream) {
    const float* x     = (const float*)d_in[0];
    const int*   ei    = (const int*)d_in[1];
    const float* ea    = (const float*)d_in[2];
    const int*   batch = (const int*)d_in[3];
    const float* W1 = (const float*)d_in[4];
    const float* b1 = (const float*)d_in[5];
    const float* W2 = (const float*)d_in[6];
    const float* b2 = (const float*)d_in[7];
    const float* W3 = (const float*)d_in[8];
    const float* b3 = (const float*)d_in[9];
    const float* Wl = (const float*)d_in[10];
    const float* bl = (const float*)d_in[11];
    float* out = (float*)d_out;
    char* ws = (char*)d_ws;

    const int* src = ei;
    const int* dst = ei + N_EDGES;

    size_t off = 0;
    auto alloc = [&](size_t bytes) { char* p = ws + off; off += (bytes + 255) & ~(size_t)255; return p; };
    float* pdeg    = (float*)alloc((size_t)NCX * PN * 4);
    int*   pcnt    = (int*)  alloc((size_t)NCX * PN * 4);
    float* dinv    = (float*)alloc(N_NODES * 4);
    int*   cnt     = (int*)  alloc((size_t)PN * 4);
    int*   partial = (int*)  alloc(SCAN_NB * 4);
    int*   rowptr  = (int*)  alloc((N_NODES + 1) * 4);
    int2*  csr     = (int2*) alloc((size_t)N_EDGES * 8);
    unsigned short* Xb  = (unsigned short*)alloc((size_t)N_NODES * 160 * 2);
    unsigned short* Y0  = (unsigned short*)alloc((size_t)N_NODES * 128 * 2);
    unsigned short* Y1  = (unsigned short*)alloc((size_t)N_NODES * 128 * 2);
    unsigned short* Y2  = (unsigned short*)alloc((size_t)N_NODES * 128 * 2);
    unsigned short* U   = (unsigned short*)alloc((size_t)N_NODES * 128 * 2);
    unsigned short* WT1 = (unsigned short*)alloc((size_t)384 * 160 * 2);
    unsigned short* WT2 = (unsigned short*)alloc((size_t)192 * 128 * 2);
    unsigned short* WT3 = (unsigned short*)alloc((size_t)96 * 64 * 2);

    const int BT = 256;

    // D1: hist + conv + wprep
    prep_kernel<<<HVB + CONVB + WPREPB, BT, 0, stream>>>(src, dst, ea, pdeg, pcnt,
                                                         x, Xb, W1, W2, W3, WT1, WT2, WT3);
    // D2: reduce + block sums
    reduce_scan_kernel<<<SCAN_NB, BT, 0, stream>>>(pdeg, pcnt, dinv, cnt, partial);
    // D3: final scan -> rowptr
    scan_final_kernel<<<SCAN_NB, BT, 0, stream>>>(cnt, partial, rowptr, N_NODES);
    // D4: scatter + layer-1 GEMM merged (10752 B LDS, unified output groups)
    sg_kernel<<<SCVB + GEMM_MB, BT, 0, stream>>>(src, dst, ea, rowptr, pcnt, csr,
                                                 Xb, WT1, dinv, Y0, Y1, Y2);

    auto gb = [&](int F) { int DPB = 256 / (F / 8); return (N_NODES + DPB - 1) / DPB; };

    gather_kernel<128, 0><<<gb(128), BT, 0, stream>>>(Y2, csr, rowptr, dinv, Y1, nullptr, U, N_NODES);
    gather_kernel<128, 1><<<gb(128), BT, 0, stream>>>(U, csr, rowptr, dinv, Y0, b1, Xb, N_NODES);

    cheb_gemm<128, 64><<<GEMM_MB, BT, 0, stream>>>(Xb, WT2, dinv, Y0, Y1, Y2, N_NODES);
    gather_kernel<64, 0><<<gb(64), BT, 0, stream>>>(Y2, csr, rowptr, dinv, Y1, nullptr, U, N_NODES);
    gather_kernel<64, 1><<<gb(64), BT, 0, stream>>>(U, csr, rowptr, dinv, Y0, b2, Xb, N_NODES);

    cheb_gemm<64, 32><<<GEMM_MB, BT, 0, stream>>>(Xb, WT3, dinv, Y0, Y1, Y2, N_NODES);
    gather_kernel<32, 0><<<gb(32), BT, 0, stream>>>(Y2, csr, rowptr, dinv, Y1, nullptr, U, N_NODES);
    gather_kernel<32, 1><<<gb(32), BT, 0, stream>>>(U, csr, rowptr, dinv, Y0, b3, Xb, N_NODES);

    pool_kernel<<<NUM_G, BT, 0, stream>>>(Xb, batch, Wl, bl, out, N_NODES);
}

// Round 7
// 288.809 us; speedup vs baseline: 1.0673x; 1.0152x over previous
//
#include <hip/hip_runtime.h>

#define N_NODES 50000
#define N_EDGES 500000
#define NUM_G   128
#define SCAN_NB 49               // ceil(50176/1024)
#define PN      (SCAN_NB * 1024) // 50176 padded node count
#define NCX     32               // edge chunks
#define NCX_SH  5
#define ECH     15628            // 32*15628 >= 500000, ECH % 4 == 0
#define RNG     8192             // nodes per LDS range for hist (32 KB)
#define NRY     7                // 7*8192 >= PN
#define HVB     (2 * NCX * NRY)  // 448 hist virtual blocks
#define WPREPB  360
#define RNG_SC  2688             // scatter cursor window (10752 B = GEMM LDS)
#define NRY_SC  19               // 19*2688 = 51072 >= 50000
#define SCVB    (NCX * NRY_SC)   // 608 scatter virtual blocks
#define GEMM_MB 782              // (50000+63)/64

typedef __attribute__((ext_vector_type(8))) short short8;
typedef __attribute__((ext_vector_type(4))) float f32x4;
typedef __attribute__((ext_vector_type(2))) float f32x2;

__device__ __forceinline__ unsigned f2bf(float x) {
    unsigned u = __float_as_uint(x);
    return (u + 0x7FFFu + ((u >> 16) & 1u)) >> 16;   // RNE
}
__device__ __forceinline__ float bf2f(unsigned h) {
    return __uint_as_float(h << 16);
}

// ============ D1: hist partials + weight prep (one dispatch; x-conv folded into sg GEMM) ============
__device__ __forceinline__ void wprep_one(const float* __restrict__ W, unsigned short* __restrict__ WT,
                                          int t, int FIN, int F) {
    int n = t / FIN, k = t - n * FIN;
    int sel = n / F, c = n - sel * F;
    float v;
    if (sel == 0) v = W[(size_t)k * F + c] - W[(size_t)2 * FIN * F + (size_t)k * F + c];
    else          v = W[(size_t)sel * FIN * F + (size_t)k * F + c];
    WT[t] = (unsigned short)f2bf(v);
}

__global__ __launch_bounds__(256)
void prep_kernel(const int* __restrict__ src, const int* __restrict__ dst,
                 const float* __restrict__ ea,
                 float* __restrict__ pdeg, int* __restrict__ pcnt,
                 const float* __restrict__ W1, const float* __restrict__ W2,
                 const float* __restrict__ W3,
                 unsigned short* __restrict__ WT1, unsigned short* __restrict__ WT2,
                 unsigned short* __restrict__ WT3) {
    __shared__ unsigned lh[RNG];
    int vb = blockIdx.x, tid = threadIdx.x;
    if (vb < HVB) {
        bool isdeg = vb < NCX * NRY;
        int v2 = isdeg ? vb : vb - NCX * NRY;
        int xk = v2 & (NCX - 1), y = v2 >> NCX_SH;
        int base = y * RNG;
        for (int i = tid; i < RNG; i += 256) lh[i] = 0u;
        __syncthreads();
        int e0 = xk * ECH, e1 = min(e0 + ECH, N_EDGES);
        if (isdeg) {
            for (int e = e0 + tid * 4; e < e1; e += 1024) {
                int4 s4 = *reinterpret_cast<const int4*>(src + e);
                if ((unsigned)(s4.x - base) < RNG) atomicAdd((float*)&lh[s4.x - base], ea[e]);
                if ((unsigned)(s4.y - base) < RNG) atomicAdd((float*)&lh[s4.y - base], ea[e + 1]);
                if ((unsigned)(s4.z - base) < RNG) atomicAdd((float*)&lh[s4.z - base], ea[e + 2]);
                if ((unsigned)(s4.w - base) < RNG) atomicAdd((float*)&lh[s4.w - base], ea[e + 3]);
            }
        } else {
            for (int e = e0 + tid * 4; e < e1; e += 1024) {
                int4 d4 = *reinterpret_cast<const int4*>(dst + e);
                if ((unsigned)(d4.x - base) < RNG) atomicAdd((int*)&lh[d4.x - base], 1);
                if ((unsigned)(d4.y - base) < RNG) atomicAdd((int*)&lh[d4.y - base], 1);
                if ((unsigned)(d4.z - base) < RNG) atomicAdd((int*)&lh[d4.z - base], 1);
                if ((unsigned)(d4.w - base) < RNG) atomicAdd((int*)&lh[d4.w - base], 1);
            }
        }
        __syncthreads();
        if (isdeg) {
            for (int i = tid; i < RNG; i += 256) {
                int n = base + i;
                if (n < PN) pdeg[(size_t)xk * PN + n] = ((float*)lh)[i];
            }
        } else {
            for (int i = tid; i < RNG; i += 256) {
                int n = base + i;
                if (n < PN) pcnt[(size_t)xk * PN + n] = ((int*)lh)[i];
            }
        }
    } else {
        int t = (vb - HVB) * 256 + tid;
        if (t < 61440)      wprep_one(W1, WT1, t, 160, 128);
        else if (t < 86016) wprep_one(W2, WT2, t - 61440, 128, 64);
        else if (t < 92160) wprep_one(W3, WT3, t - 86016, 64, 32);
    }
}

// ==== D2: reduce partials -> dinv, cnt; pcnt -> exclusive chunk-prefix; block sums ====
__global__ __launch_bounds__(256)
void reduce_scan_kernel(const float* __restrict__ pdeg, int* __restrict__ pcnt,
                        float* __restrict__ dinv, int* __restrict__ cnt,
                        int* __restrict__ partial) {
    int b = blockIdx.x, t = threadIdx.x;
    int i0 = b * 1024 + t * 4;
    float d0 = 0.f, d1 = 0.f, d2 = 0.f, d3 = 0.f;
    int r0 = 0, r1 = 0, r2 = 0, r3 = 0;
    for (int x = 0; x < NCX; ++x) {
        float4 pv = *reinterpret_cast<const float4*>(pdeg + (size_t)x * PN + i0);
        int4   cv = *reinterpret_cast<const int4*>(pcnt + (size_t)x * PN + i0);
        *reinterpret_cast<int4*>(pcnt + (size_t)x * PN + i0) = make_int4(r0, r1, r2, r3);
        d0 += pv.x; d1 += pv.y; d2 += pv.z; d3 += pv.w;
        r0 += cv.x; r1 += cv.y; r2 += cv.z; r3 += cv.w;
    }
    float dd[4] = {d0, d1, d2, d3};
    int   rr[4] = {r0, r1, r2, r3};
    int s = 0;
    #pragma unroll
    for (int j = 0; j < 4; ++j) {
        int n = i0 + j;
        if (n < N_NODES) {
            float dv = dd[j], r = 0.f;
            if (dv > 0.f) {
                r = rsqrtf(dv);
                r = r * (1.5f - 0.5f * dv * r * r);   // Newton refine to ~fp32 exact
            }
            dinv[n] = r;
            cnt[n] = rr[j];
            s += rr[j];
        } else {
            cnt[n] = 0;
        }
    }
    __shared__ int red[256];
    red[t] = s;
    __syncthreads();
    for (int off = 128; off > 0; off >>= 1) {
        if (t < off) red[t] += red[t + off];
        __syncthreads();
    }
    if (t == 0) partial[b] = red[0];
}

// ==== D3: final scan -> rowptr (each block redundantly wave-scans the 49 partials) ====
__global__ __launch_bounds__(256)
void scan_final_kernel(const int* __restrict__ cnt, const int* __restrict__ partial,
                       int* __restrict__ rowptr, int n) {
    int b = blockIdx.x, t = threadIdx.x;
    __shared__ int red[256];
    __shared__ int sh_off, sh_tot;
    if (t < 64) {
        int orig = (t < SCAN_NB) ? partial[t] : 0;
        int v = orig;
        #pragma unroll
        for (int off = 1; off < 64; off <<= 1) {
            int u = __shfl_up(v, off, 64);
            if (t >= off) v += u;
        }
        if (t == b) sh_off = v - orig;            // this block's exclusive offset (b < 49 <= 63)
        if (t == SCAN_NB - 1) sh_tot = v;         // grand total
    }
    __syncthreads();
    int4 v = reinterpret_cast<const int4*>(cnt)[b * 256 + t];
    int s = v.x + v.y + v.z + v.w;
    red[t] = s;
    __syncthreads();
    for (int off = 1; off < 256; off <<= 1) {
        int u = (t >= off) ? red[t - off] : 0;
        __syncthreads();
        red[t] += u;
        __syncthreads();
    }
    int excl = sh_off + ((t == 0) ? 0 : red[t - 1]);
    int i0 = b * 1024 + t * 4;
    if (i0 < n)     rowptr[i0]     = excl;
    if (i0 + 1 < n) rowptr[i0 + 1] = excl + v.x;
    if (i0 + 2 < n) rowptr[i0 + 2] = excl + v.x + v.y;
    if (i0 + 3 < n) rowptr[i0 + 3] = excl + v.x + v.y + v.z;
    if (b == SCAN_NB - 1 && t == 0) rowptr[n] = sh_tot;
}

// ==== shared bodies for the merged D4 dispatch ====
__device__ void scatter_body(int vb, const int* __restrict__ src, const int* __restrict__ dst,
                             const float* __restrict__ ea,
                             const int* __restrict__ rowptr, const int* __restrict__ pcnt,
                             int2* __restrict__ csr, unsigned char* smraw) {
    int* cursor = (int*)smraw;
    int tid = threadIdx.x;
    int x = vb & (NCX - 1), y = vb >> NCX_SH;
    int base = y * RNG_SC;
    for (int i = tid; i < RNG_SC; i += 256) {
        int n = base + i;
        cursor[i] = (n < N_NODES) ? (rowptr[n] + pcnt[(size_t)x * PN + n]) : 0;
    }
    __syncthreads();
    int e0 = x * ECH, e1 = min(e0 + ECH, N_EDGES);
    for (int e = e0 + tid * 4; e < e1; e += 1024) {
        int4 d4 = *reinterpret_cast<const int4*>(dst + e);
        if ((unsigned)(d4.x - base) < RNG_SC) {
            int pos = atomicAdd(&cursor[d4.x - base], 1);
            csr[pos] = make_int2(src[e], __float_as_int(ea[e]));
        }
        if ((unsigned)(d4.y - base) < RNG_SC) {
            int pos = atomicAdd(&cursor[d4.y - base], 1);
            csr[pos] = make_int2(src[e + 1], __float_as_int(ea[e + 1]));
        }
        if ((unsigned)(d4.z - base) < RNG_SC) {
            int pos = atomicAdd(&cursor[d4.z - base], 1);
            csr[pos] = make_int2(src[e + 2], __float_as_int(ea[e + 2]));
        }
        if ((unsigned)(d4.w - base) < RNG_SC) {
            int pos = atomicAdd(&cursor[d4.w - base], 1);
            csr[pos] = make_int2(src[e + 3], __float_as_int(ea[e + 3]));
        }
    }
}

// Unified-group GEMM: one block computes all 3 output groups for its 64 rows.
// AFP32: A matrix is fp32 (layer 1 reads x directly, converts in-register).
template<int FIN, int F, bool AFP32>
__device__ void gemm_body(int bx, const void* __restrict__ Araw,
                          const unsigned short* __restrict__ WT, const float* __restrict__ dinv,
                          unsigned short* __restrict__ Y0, unsigned short* __restrict__ Y1,
                          unsigned short* __restrict__ Y2, int nrows, unsigned char* smraw) {
    constexpr int KT = FIN / 32;
    constexpr int NT = F / 32;       // tiles per group
    constexpr int NTT = 3 * NT;      // total tiles
    constexpr int SA = FIN + 8;
    constexpr int F8 = FIN / 8;
    short* Bs = (short*)smraw;

    int tid = threadIdx.x;
    int lane = tid & 63, w = tid >> 6;
    int m0 = bx * 64;

    int colb = lane & 15;
    int q8 = (lane >> 4) << 3;
    int rq = (lane >> 4) << 2;
    int arow = m0 + w * 16 + colb;
    bool rok = arow < nrows;

    short8 afr[KT];
    #pragma unroll
    for (int kt = 0; kt < KT; ++kt) {
        short8 z = {0, 0, 0, 0, 0, 0, 0, 0};
        if (!rok) { afr[kt] = z; continue; }
        if constexpr (AFP32) {
            const float* A = (const float*)Araw;
            float4 f0 = *reinterpret_cast<const float4*>(A + (size_t)arow * FIN + (kt << 5) + q8);
            float4 f1 = *reinterpret_cast<const float4*>(A + (size_t)arow * FIN + (kt << 5) + q8 + 4);
            short8 r;
            r[0] = (short)f2bf(f0.x); r[1] = (short)f2bf(f0.y);
            r[2] = (short)f2bf(f0.z); r[3] = (short)f2bf(f0.w);
            r[4] = (short)f2bf(f1.x); r[5] = (short)f2bf(f1.y);
            r[6] = (short)f2bf(f1.z); r[7] = (short)f2bf(f1.w);
            afr[kt] = r;
        } else {
            const unsigned short* A = (const unsigned short*)Araw;
            afr[kt] = *reinterpret_cast<const short8*>(A + (size_t)arow * FIN + (kt << 5) + q8);
        }
    }

    for (int nt = 0; nt < NTT; ++nt) {
        int n0 = nt << 5;
        __syncthreads();
        for (int span = tid; span < 32 * F8; span += 256) {
            int r = span / F8, c8 = (span - r * F8) << 3;
            int pr = (r < 16) ? (r << 1) : (((r - 16) << 1) + 1);
            *reinterpret_cast<uint4*>(&Bs[r * SA + c8]) =
                *reinterpret_cast<const uint4*>(WT + (size_t)(n0 + pr) * FIN + c8);
        }
        __syncthreads();

        f32x4 acc0 = {0.f, 0.f, 0.f, 0.f}, acc1 = acc0;
        #pragma unroll
        for (int kt = 0; kt < KT; ++kt) {
            short8 b0 = *reinterpret_cast<const short8*>(&Bs[colb * SA + (kt << 5) + q8]);
            short8 b1 = *reinterpret_cast<const short8*>(&Bs[(colb + 16) * SA + (kt << 5) + q8]);
            acc0 = __builtin_amdgcn_mfma_f32_16x16x32_bf16(afr[kt], b0, acc0, 0, 0, 0);
            acc1 = __builtin_amdgcn_mfma_f32_16x16x32_bf16(afr[kt], b1, acc1, 0, 0, 0);
        }

        int g = nt / NT;
        int ntg = nt - g * NT;
        unsigned short* Ys = (g == 0) ? Y0 : (g == 1) ? Y1 : Y2;
        int lc = (ntg << 5) + (colb << 1);
        #pragma unroll
        for (int r = 0; r < 4; ++r) {
            int orow = m0 + w * 16 + rq + r;
            if (orow < nrows) {
                float sc = (g == 2) ? dinv[orow] : 1.0f;
                unsigned pack = f2bf(acc0[r] * sc) | (f2bf(acc1[r] * sc) << 16);
                *reinterpret_cast<unsigned*>(Ys + (size_t)orow * F + lc) = pack;
            }
        }
    }
}

// ==== D4: merged scatter + layer-1 GEMM (A = x in fp32, converted in-register) ====
__global__ __launch_bounds__(256)
void sg_kernel(const int* __restrict__ src, const int* __restrict__ dst,
               const float* __restrict__ ea,
               const int* __restrict__ rowptr, const int* __restrict__ pcnt,
               int2* __restrict__ csr,
               const float* __restrict__ x, const unsigned short* __restrict__ WT1,
               const float* __restrict__ dinv,
               unsigned short* __restrict__ Y0, unsigned short* __restrict__ Y1,
               unsigned short* __restrict__ Y2) {
    __shared__ alignas(16) unsigned char sm[32 * (160 + 8) * 2];   // 10752 B
    int vb = blockIdx.x;
    if (vb < SCVB) {
        scatter_body(vb, src, dst, ea, rowptr, pcnt, csr, sm);
    } else {
        gemm_body<160, 128, true>(vb - SCVB, x, WT1, dinv, Y0, Y1, Y2, N_NODES, sm);
    }
}

// ==== layers 2/3 GEMM (unified groups) ====
template<int FIN, int F>
__launch_bounds__(256)
__global__ void cheb_gemm(const unsigned short* __restrict__ Xb, const unsigned short* __restrict__ WT,
                          const float* __restrict__ dinv,
                          unsigned short* __restrict__ Y0, unsigned short* __restrict__ Y1,
                          unsigned short* __restrict__ Y2, int nrows) {
    __shared__ alignas(16) unsigned char sm[32 * (FIN + 8) * 2];
    gemm_body<FIN, F, false>(blockIdx.x, Xb, WT, dinv, Y0, Y1, Y2, nrows, sm);
}

// ============ bf16 CSR gathers: sorted rows + predicated full-ILP 8-batches ============
// f32x2-packed accumulate: 4 lshl + 4 and + 4 v_pk_fma_f32 per 16B
__device__ __forceinline__ void acc8p(f32x2* acc, uint4 p, float wv) {
    f32x2 w2; w2[0] = wv; w2[1] = wv;
    f32x2 a0, a1, a2, a3;
    a0[0] = __uint_as_float(p.x << 16); a0[1] = __uint_as_float(p.x & 0xFFFF0000u);
    a1[0] = __uint_as_float(p.y << 16); a1[1] = __uint_as_float(p.y & 0xFFFF0000u);
    a2[0] = __uint_as_float(p.z << 16); a2[1] = __uint_as_float(p.z & 0xFFFF0000u);
    a3[0] = __uint_as_float(p.w << 16); a3[1] = __uint_as_float(p.w & 0xFFFF0000u);
    acc[0] += w2 * a0;
    acc[1] += w2 * a1;
    acc[2] += w2 * a2;
    acc[3] += w2 * a3;
}

__device__ __forceinline__ void expand8(uint4 p, float* o) {
    o[0] = bf2f(p.x & 0xFFFFu);
    o[1] = __uint_as_float(p.x & 0xFFFF0000u);
    o[2] = bf2f(p.y & 0xFFFFu);
    o[3] = __uint_as_float(p.y & 0xFFFF0000u);
    o[4] = bf2f(p.z & 0xFFFFu);
    o[5] = __uint_as_float(p.z & 0xFFFF0000u);
    o[6] = bf2f(p.w & 0xFFFFu);
    o[7] = __uint_as_float(p.w & 0xFFFF0000u);
}

// MODE 0: U' = dv*(Y - 2*dv*t) ;  MODE 1: relu(Y - dv*t + bias)
template<int F, int MODE>
__launch_bounds__(256)
__global__ void gather_kernel(const unsigned short* __restrict__ X, const int2* __restrict__ csr,
                              const int* __restrict__ rowptr, const float* __restrict__ dinv,
                              const unsigned short* __restrict__ Y, const float* __restrict__ bias,
                              unsigned short* __restrict__ O, int n) {
    constexpr int FQ8 = F >> 3;            // threads per row: 16/8/4
    constexpr int DPB = 256 / FQ8;         // rows per block: 16/32/64
    constexpr int CAP = 1280;              // staged edge capacity (10.2 KB; worst block ~Poisson(640))
    __shared__ int2 scsr[CAP];
    __shared__ int srp[DPB + 1];
    __shared__ int smap[DPB];              // rank -> row slot (length-sorted)
    int tid = threadIdx.x;
    int db0 = blockIdx.x * DPB;
    if (tid <= DPB) srp[tid] = rowptr[min(db0 + tid, n)];
    __syncthreads();
    int ebeg = srp[0];
    int ecnt = srp[DPB] - ebeg;
    bool staged = ecnt <= CAP;
    // rank rows by CSR length (ascending, ties by slot) so each wave's groups
    // carry near-equal edge counts -> minimal lockstep waste. Deterministic.
    if (tid < DPB) {
        int my = srp[tid + 1] - srp[tid];
        int rk = 0;
        for (int g2 = 0; g2 < DPB; ++g2) {
            int l2 = srp[g2 + 1] - srp[g2];
            rk += (l2 < my) || (l2 == my && g2 < tid);
        }
        smap[rk] = tid;
    }
    if (staged) {
        for (int i = tid; i < ecnt; i += 256)
            scsr[i] = csr[ebeg + i];
    }
    __syncthreads();

    int gq = tid / FQ8;
    int rr = smap[gq];                     // this group's (sorted) row slot
    int d = db0 + rr;
    if (d >= n) return;                    // zero-length pad rows sort to the front
    int f8 = (tid - gq * FQ8) << 3;
    f32x2 acc[4];
    #pragma unroll
    for (int j = 0; j < 4; ++j) { acc[j][0] = 0.f; acc[j][1] = 0.f; }

    if (staged) {
        int beg = srp[rr] - ebeg, end = srp[rr + 1] - ebeg;
        int last = end - 1;
        // predicated 8-batches: every row takes ceil(L/8) full-ILP rounds, no
        // serial tail. Overhang lanes clamp to the row's last edge (same cache
        // line, just fetched) with weight forced to 0 -> exact no-op.
        for (int i = beg; i < end; i += 8) {
            int2 e0 = scsr[i];
            int2 e1 = scsr[min(i + 1, last)];
            int2 e2 = scsr[min(i + 2, last)];
            int2 e3 = scsr[min(i + 3, last)];
            int2 e4 = scsr[min(i + 4, last)];
            int2 e5 = scsr[min(i + 5, last)];
            int2 e6 = scsr[min(i + 6, last)];
            int2 e7 = scsr[min(i + 7, last)];
            uint4 p0 = *reinterpret_cast<const uint4*>(X + (size_t)e0.x * F + f8);
            uint4 p1 = *reinterpret_cast<const uint4*>(X + (size_t)e1.x * F + f8);
            uint4 p2 = *reinterpret_cast<const uint4*>(X + (size_t)e2.x * F + f8);
            uint4 p3 = *reinterpret_cast<const uint4*>(X + (size_t)e3.x * F + f8);
            uint4 p4 = *reinterpret_cast<const uint4*>(X + (size_t)e4.x * F + f8);
            uint4 p5 = *reinterpret_cast<const uint4*>(X + (size_t)e5.x * F + f8);
            uint4 p6 = *reinterpret_cast<const uint4*>(X + (size_t)e6.x * F + f8);
            uint4 p7 = *reinterpret_cast<const uint4*>(X + (size_t)e7.x * F + f8);
            float w0 = __int_as_float(e0.y);
            float w1 = (i + 1 < end) ? __int_as_float(e1.y) : 0.f;
            float w2 = (i + 2 < end) ? __int_as_float(e2.y) : 0.f;
            float w3 = (i + 3 < end) ? __int_as_float(e3.y) : 0.f;
            float w4 = (i + 4 < end) ? __int_as_float(e4.y) : 0.f;
            float w5 = (i + 5 < end) ? __int_as_float(e5.y) : 0.f;
            float w6 = (i + 6 < end) ? __int_as_float(e6.y) : 0.f;
            float w7 = (i + 7 < end) ? __int_as_float(e7.y) : 0.f;
            acc8p(acc, p0, w0);
            acc8p(acc, p1, w1);
            acc8p(acc, p2, w2);
            acc8p(acc, p3, w3);
            acc8p(acc, p4, w4);
            acc8p(acc, p5, w5);
            acc8p(acc, p6, w6);
            acc8p(acc, p7, w7);
        }
    } else {                               // fallback: direct global (never expected)
        int beg = srp[rr], end = srp[rr + 1];
        for (int i = beg; i < end; ++i) {
            int2 e = csr[i];
            uint4 p = *reinterpret_cast<const uint4*>(X + (size_t)e.x * F + f8);
            acc8p(acc, p, __int_as_float(e.y));
        }
    }

    float accs[8];
    #pragma unroll
    for (int j = 0; j < 8; ++j) accs[j] = acc[j >> 1][j & 1];

    float y[8];
    expand8(*reinterpret_cast<const uint4*>(Y + (size_t)d * F + f8), y);
    float dv = dinv[d];
    float v[8];
    if (MODE == 0) {
        float dv2 = 2.f * dv;
        #pragma unroll
        for (int j = 0; j < 8; ++j) v[j] = dv * (y[j] - dv2 * accs[j]);
    } else {
        float4 ba = *reinterpret_cast<const float4*>(bias + f8);
        float4 bb = *reinterpret_cast<const float4*>(bias + f8 + 4);
        v[0] = fmaxf(y[0] - dv * accs[0] + ba.x, 0.f);
        v[1] = fmaxf(y[1] - dv * accs[1] + ba.y, 0.f);
        v[2] = fmaxf(y[2] - dv * accs[2] + ba.z, 0.f);
        v[3] = fmaxf(y[3] - dv * accs[3] + ba.w, 0.f);
        v[4] = fmaxf(y[4] - dv * accs[4] + bb.x, 0.f);
        v[5] = fmaxf(y[5] - dv * accs[5] + bb.y, 0.f);
        v[6] = fmaxf(y[6] - dv * accs[6] + bb.z, 0.f);
        v[7] = fmaxf(y[7] - dv * accs[7] + bb.w, 0.f);
    }
    uint4 o;
    o.x = f2bf(v[0]) | (f2bf(v[1]) << 16);
    o.y = f2bf(v[2]) | (f2bf(v[3]) << 16);
    o.z = f2bf(v[4]) | (f2bf(v[5]) << 16);
    o.w = f2bf(v[6]) | (f2bf(v[7]) << 16);
    *reinterpret_cast<uint4*>(O + (size_t)d * F + f8) = o;
}

// ============ pooling + final linear ============
__device__ __forceinline__ int lower_bound_dev(const int* __restrict__ a, int n, int v) {
    int lo = 0, hi = n;
    while (lo < hi) {
        int mid = (lo + hi) >> 1;
        if (a[mid] < v) lo = mid + 1; else hi = mid;
    }
    return lo;
}

__global__ void pool_kernel(const unsigned short* __restrict__ H, const int* __restrict__ batch,
                            const float* __restrict__ Wl, const float* __restrict__ bl,
                            float* __restrict__ out, int n) {
    int g = blockIdx.x;
    int start = lower_bound_dev(batch, n, g);
    int end   = lower_bound_dev(batch, n, g + 1);
    int tid = threadIdx.x;
    int f = tid & 31;
    int sub = tid >> 5;
    float acc = 0.0f;
    for (int i = start + sub; i < end; i += 8)
        acc += bf2f((unsigned)H[(size_t)i * 32 + f]);
    __shared__ float red[256];
    red[tid] = acc;
    __syncthreads();
    if (tid < 128) red[tid] += red[tid + 128];
    __syncthreads();
    if (tid < 64) red[tid] += red[tid + 64];
    __syncthreads();
    if (tid < 32) red[tid] += red[tid + 32];
    __syncthreads();
    if (tid < 2) {
        int cnt = end - start;
        float inv = 1.0f / (float)(cnt > 0 ? cnt : 1);
        float o = bl[tid];
        for (int f2 = 0; f2 < 32; ++f2)
            o += red[f2] * inv * Wl[f2 * 2 + tid];
        out[g * 2 + tid] = o;
    }
}

extern "C" void kernel_launch(void* const* d_in, const int* in_sizes, int n_in,
                              void* d_out, int out_size, void* d_ws, size_t ws_size,
                              hipStream_t stream) {
    const float* x     = (const float*)d_in[0];
    const int*   ei    = (const int*)d_in[1];
    const float* ea    = (const float*)d_in[2];
    const int*   batch = (const int*)d_in[3];
    const float* W1 = (const float*)d_in[4];
    const float* b1 = (const float*)d_in[5];
    const float* W2 = (const float*)d_in[6];
    const float* b2 = (const float*)d_in[7];
    const float* W3 = (const float*)d_in[8];
    const float* b3 = (const float*)d_in[9];
    const float* Wl = (const float*)d_in[10];
    const float* bl = (const float*)d_in[11];
    float* out = (float*)d_out;
    char* ws = (char*)d_ws;

    const int* src = ei;
    const int* dst = ei + N_EDGES;

    size_t off = 0;
    auto alloc = [&](size_t bytes) { char* p = ws + off; off += (bytes + 255) & ~(size_t)255; return p; };
    float* pdeg    = (float*)alloc((size_t)NCX * PN * 4);
    int*   pcnt    = (int*)  alloc((size_t)NCX * PN * 4);
    float* dinv    = (float*)alloc(N_NODES * 4);
    int*   cnt     = (int*)  alloc((size_t)PN * 4);
    int*   partial = (int*)  alloc(SCAN_NB * 4);
    int*   rowptr  = (int*)  alloc((N_NODES + 1) * 4);
    int2*  csr     = (int2*) alloc((size_t)N_EDGES * 8);
    unsigned short* Xb  = (unsigned short*)alloc((size_t)N_NODES * 160 * 2);
    unsigned short* Y0  = (unsigned short*)alloc((size_t)N_NODES * 128 * 2);
    unsigned short* Y1  = (unsigned short*)alloc((size_t)N_NODES * 128 * 2);
    unsigned short* Y2  = (unsigned short*)alloc((size_t)N_NODES * 128 * 2);
    unsigned short* U   = (unsigned short*)alloc((size_t)N_NODES * 128 * 2);
    unsigned short* WT1 = (unsigned short*)alloc((size_t)384 * 160 * 2);
    unsigned short* WT2 = (unsigned short*)alloc((size_t)192 * 128 * 2);
    unsigned short* WT3 = (unsigned short*)alloc((size_t)96 * 64 * 2);

    const int BT = 256;

    // D1: hist + wprep (x-conv folded into sg's layer-1 GEMM)
    prep_kernel<<<HVB + WPREPB, BT, 0, stream>>>(src, dst, ea, pdeg, pcnt,
                                                 W1, W2, W3, WT1, WT2, WT3);
    // D2: reduce + block sums
    reduce_scan_kernel<<<SCAN_NB, BT, 0, stream>>>(pdeg, pcnt, dinv, cnt, partial);
    // D3: final scan -> rowptr
    scan_final_kernel<<<SCAN_NB, BT, 0, stream>>>(cnt, partial, rowptr, N_NODES);
    // D4: scatter + layer-1 GEMM merged (reads x fp32 directly)
    sg_kernel<<<SCVB + GEMM_MB, BT, 0, stream>>>(src, dst, ea, rowptr, pcnt, csr,
                                                 x, WT1, dinv, Y0, Y1, Y2);

    auto gb = [&](int F) { int DPB = 256 / (F / 8); return (N_NODES + DPB - 1) / DPB; };

    gather_kernel<128, 0><<<gb(128), BT, 0, stream>>>(Y2, csr, rowptr, dinv, Y1, nullptr, U, N_NODES);
    gather_kernel<128, 1><<<gb(128), BT, 0, stream>>>(U, csr, rowptr, dinv, Y0, b1, Xb, N_NODES);

    cheb_gemm<128, 64><<<GEMM_MB, BT, 0, stream>>>(Xb, WT2, dinv, Y0, Y1, Y2, N_NODES);
    gather_kernel<64, 0><<<gb(64), BT, 0, stream>>>(Y2, csr, rowptr, dinv, Y1, nullptr, U, N_NODES);
    gather_kernel<64, 1><<<gb(64), BT, 0, stream>>>(U, csr, rowptr, dinv, Y0, b2, Xb, N_NODES);

    cheb_gemm<64, 32><<<GEMM_MB, BT, 0, stream>>>(Xb, WT3, dinv, Y0, Y1, Y2, N_NODES);
    gather_kernel<32, 0><<<gb(32), BT, 0, stream>>>(Y2, csr, rowptr, dinv, Y1, nullptr, U, N_NODES);
    gather_kernel<32, 1><<<gb(32), BT, 0, stream>>>(U, csr, rowptr, dinv, Y0, b3, Xb, N_NODES);

    pool_kernel<<<NUM_G, BT, 0, stream>>>(Xb, batch, Wl, bl, out, N_NODES);
}